// Round 6
// baseline (117.267 us; speedup 1.0000x reference)
//
#include <hip/hip_runtime.h>
#include <hip/hip_bf16.h>
#include <math.h>

#define N_ 4
#define C_ 1024
#define D_ 768
#define H_ 12
#define E_ 32
#define M_ 4
#define P_ 256
#define NL_ 97
#define NLP_ 112
#define NP_ (N_*P_)
#define K3D_ 2304
#define KBL_ 49152

typedef __attribute__((ext_vector_type(8))) short short8;
typedef __attribute__((ext_vector_type(4))) float f32x4;
typedef __attribute__((ext_vector_type(4))) unsigned short ushort4v;

__device__ __forceinline__ short f2bf(float x){
  union { __hip_bfloat16 h; short s; } u; u.h = __float2bfloat16(x); return u.s;
}
__device__ __forceinline__ unsigned short f2bfu(float x){
  union { __hip_bfloat16 h; unsigned short s; } u; u.h = __float2bfloat16(x); return u.s;
}
__device__ __forceinline__ float bf2f(unsigned short u){
  union { unsigned int i; float f; } x; x.i = ((unsigned int)u)<<16; return x.f;
}

__device__ __forceinline__ float blockReduceSum256(float v){
  __shared__ float red_s[4];
  #pragma unroll
  for (int o=32;o>0;o>>=1) v += __shfl_down(v, o);
  if ((threadIdx.x & 63)==0) red_s[threadIdx.x>>6] = v;
  __syncthreads();
  float t = red_s[0]+red_s[1]+red_s[2]+red_s[3];
  __syncthreads();
  return t;
}

// transpose+cvt 64(R)x32(C) tile: in [R][C] f32 -> out [Cp][R] bf16, zero-pad c>=C
__device__ __forceinline__ void tcvt64(const float* __restrict__ in,
    __hip_bfloat16* __restrict__ out, int R, int C, int Cp, int tile){
  __shared__ float tb[64][33];
  const int tiles_c = (Cp + 31) >> 5;
  const int rb = (tile/tiles_c)*64, cb = (tile%tiles_c)*32;
  const int tid = threadIdx.x;
  const bool vec = ((C & 3) == 0);
  #pragma unroll
  for (int i=0;i<2;i++){
    const int idx = tid + i*256;
    const int row = idx>>3, c4 = (idx&7)*4;
    const int c = cb + c4;
    float v0=0.f,v1=0.f,v2=0.f,v3=0.f;
    if (vec && c+3 < C){
      const f32x4 v = *(const f32x4*)&in[(size_t)(rb+row)*C + c];
      v0=v[0]; v1=v[1]; v2=v[2]; v3=v[3];
    } else {
      const float* rp = in + (size_t)(rb+row)*C;
      if (c   < C) v0 = rp[c];
      if (c+1 < C) v1 = rp[c+1];
      if (c+2 < C) v2 = rp[c+2];
      if (c+3 < C) v3 = rp[c+3];
    }
    tb[row][c4]=v0; tb[row][c4+1]=v1; tb[row][c4+2]=v2; tb[row][c4+3]=v3;
  }
  __syncthreads();
  #pragma unroll
  for (int i=0;i<4;i++){
    const int idx = tid + i*256;
    const int cr = idx>>5, p = idx&31;
    const int cc = cb + cr;
    if (cc < Cp){
      union { struct { unsigned short a,b; } s; unsigned int u; } pk;
      pk.s.a = f2bfu(tb[2*p][cr]);
      pk.s.b = f2bfu(tb[2*p+1][cr]);
      *(unsigned int*)&out[(size_t)cc*R + rb + 2*p] = pk.u;
    }
  }
}

// prep block ranges
#define T_WH 864            // (2304/64)*24
#define T_WT 864
#define T_WK 288            // (768/64)*24
#define T_WB 3072           // (49152/64)*4   (ceil(112/32)=4)
#define T_SEQ 1536          // (4096/64)*24
#define O_WT  (T_WH)
#define O_WK  (O_WT+T_WT)
#define O_WB  (O_WK+T_WK)
#define O_SEQ (O_WB+T_WB)
#define O_EMB (O_SEQ+T_SEQ)
#define O_ATT (O_EMB+N_*E_)
#define O_VQ  (O_ATT+N_*E_*H_)
#define O_WKAW (O_VQ+D_)
#define O_MISC (O_WKAW+D_)
#define G_PREP (O_MISC+1)

__global__ __launch_bounds__(256) void k_prep(
    const float* __restrict__ seq, const float* __restrict__ attn,
    const int* __restrict__ pos,
    const float* __restrict__ Wq, const float* __restrict__ bq,
    const float* __restrict__ Wk, const float* __restrict__ bk,
    const float* __restrict__ aw, const float* __restrict__ ab,
    const float* __restrict__ Wh, const float* __restrict__ Wt,
    const float* __restrict__ Wb,
    __hip_bfloat16* __restrict__ WhT, __hip_bfloat16* __restrict__ WtT,
    __hip_bfloat16* __restrict__ WkT, __hip_bfloat16* __restrict__ WbT,
    __hip_bfloat16* __restrict__ seqT,
    __hip_bfloat16* __restrict__ ent_bf, __hip_bfloat16* __restrict__ Ambf,
    __hip_bfloat16* __restrict__ att_bf,
    float* __restrict__ vq, float* __restrict__ wk_aw, float* __restrict__ qc2){
  const int b = blockIdx.x;
  const int tid = threadIdx.x;
  if (b < O_WT){ tcvt64(Wh, WhT, K3D_, D_, D_, b); return; }
  if (b < O_WK){ tcvt64(Wt, WtT, K3D_, D_, D_, b-O_WT); return; }
  if (b < O_WB){ tcvt64(Wk, WkT, D_, D_, D_, b-O_WK); return; }
  if (b < O_SEQ){ tcvt64(Wb, WbT, KBL_, NL_, NLP_, b-O_WB); return; }
  if (b < O_EMB){ tcvt64(seq, seqT, N_*C_, D_, D_, b-O_SEQ); return; }
  if (b < O_ATT){
    const int be = b - O_EMB;
    const int n = be >> 5;
    const int* pp = pos + be*M_;
    if (tid < 192){
      const int c4 = tid*4;
      const f32x4 v0 = *(const f32x4*)&seq[((size_t)n*C_ + pp[0])*D_ + c4];
      const f32x4 v1 = *(const f32x4*)&seq[((size_t)n*C_ + pp[1])*D_ + c4];
      const f32x4 v2 = *(const f32x4*)&seq[((size_t)n*C_ + pp[2])*D_ + c4];
      const f32x4 v3 = *(const f32x4*)&seq[((size_t)n*C_ + pp[3])*D_ + c4];
      ushort4v a0,a1,a2,a3,e;
      #pragma unroll
      for (int j=0;j<4;j++){
        a0[j]=f2bfu(v0[j]); a1[j]=f2bfu(v1[j]); a2[j]=f2bfu(v2[j]); a3[j]=f2bfu(v3[j]);
        const float m = fmaxf(fmaxf(v0[j],v1[j]), fmaxf(v2[j],v3[j]));
        const float s = expf(v0[j]-m)+expf(v1[j]-m)+expf(v2[j]-m)+expf(v3[j]-m);
        e[j] = f2bfu(m + logf(s));
      }
      *(ushort4v*)&Ambf[(size_t)(be*4+0)*D_ + c4] = a0;
      *(ushort4v*)&Ambf[(size_t)(be*4+1)*D_ + c4] = a1;
      *(ushort4v*)&Ambf[(size_t)(be*4+2)*D_ + c4] = a2;
      *(ushort4v*)&Ambf[(size_t)(be*4+3)*D_ + c4] = a3;
      *(ushort4v*)&ent_bf[(size_t)be*D_ + c4] = e;
    }
    return;
  }
  if (b < O_VQ){
    const int bb2 = b - O_ATT;          // (n*E+e)*H + h
    const int h = bb2 % H_;
    const int ne = bb2 / H_;
    const int n = ne >> 5;
    const int* pp = pos + ne*M_;
    const float* basep = attn + ((size_t)(n*H_+h))*C_*C_;
    const int c4 = tid*4;
    const f32x4 r0 = *(const f32x4*)&basep[(size_t)pp[0]*C_ + c4];
    const f32x4 r1 = *(const f32x4*)&basep[(size_t)pp[1]*C_ + c4];
    const f32x4 r2 = *(const f32x4*)&basep[(size_t)pp[2]*C_ + c4];
    const f32x4 r3 = *(const f32x4*)&basep[(size_t)pp[3]*C_ + c4];
    ushort4v o;
    #pragma unroll
    for (int j=0;j<4;j++) o[j] = f2bfu(0.25f*(r0[j]+r1[j]+r2[j]+r3[j]));
    *(ushort4v*)&att_bf[(size_t)bb2*C_ + c4] = o;
    return;
  }
  if (b < O_WKAW){
    const int k = b - O_VQ;
    float s = 0.f;
    for (int d=tid; d<D_; d+=256) s += Wq[(size_t)k*D_+d]*aw[d];
    s = blockReduceSum256(s);
    if (tid==0) vq[k] = s;
    return;
  }
  if (b < O_MISC){
    const int k = b - O_WKAW;
    float s = 0.f;
    for (int d=tid; d<D_; d+=256) s += Wk[(size_t)k*D_+d]*aw[D_+d];
    s = blockReduceSum256(s);
    if (tid==0) wk_aw[k] = s;
    return;
  }
  {
    float s0 = 0.f, s1 = 0.f;
    for (int d=tid; d<D_; d+=256){ s0 += bq[d]*aw[d]; s1 += bk[d]*aw[D_+d]; }
    s0 = blockReduceSum256(s0);
    s1 = blockReduceSum256(s1);
    if (tid==0){ qc2[0] = s0 + ab[0]; qc2[1] = s1; }
  }
}

// ht_att (bf16 in/out) + kdot[512]
__global__ __launch_bounds__(256) void k_ht2(
    const __hip_bfloat16* __restrict__ att_bf, const int* __restrict__ hts,
    const __hip_bfloat16* __restrict__ Ambf, const float* __restrict__ wk_aw,
    const float* __restrict__ qc2,
    __hip_bfloat16* __restrict__ ht_bf, float* __restrict__ kdot){
  const int b = blockIdx.x, tid = threadIdx.x;
  if (b < NP_){
    const int r = b, n = r >> 8;
    const int he = hts[r*2], te = hts[r*2+1];
    const unsigned short* ha = (const unsigned short*)att_bf + ((size_t)(n*E_+he))*H_*C_;
    const unsigned short* ta = (const unsigned short*)att_bf + ((size_t)(n*E_+te))*H_*C_;
    const int c0 = tid*4;
    float v[4] = {0.f,0.f,0.f,0.f};
    #pragma unroll
    for (int h=0;h<H_;h++){
      const ushort4v a = *(const ushort4v*)&ha[h*C_ + c0];
      const ushort4v t = *(const ushort4v*)&ta[h*C_ + c0];
      #pragma unroll
      for (int j=0;j<4;j++) v[j] = fmaf(bf2f(a[j]), bf2f(t[j]), v[j]);
    }
    float local = 0.f;
    #pragma unroll
    for (int j=0;j<4;j++){ v[j] *= (1.0f/H_); local += v[j]; }
    const float tot = blockReduceSum256(local);
    const float inv = 1.f/(tot + 1e-5f);
    ushort4v o;
    #pragma unroll
    for (int j=0;j<4;j++) o[j] = f2bfu(v[j]*inv);
    *(ushort4v*)&ht_bf[(size_t)r*C_ + c0] = o;
  } else {
    const int g = b - NP_;           // 0..511
    const unsigned short* Am = (const unsigned short*)Ambf + (size_t)g*D_;
    float s = 0.f;
    for (int d=tid; d<D_; d+=256) s += bf2f(Am[d])*wk_aw[d];
    s = blockReduceSum256(s);
    if (tid==0) kdot[g] = s + qc2[1];
  }
}

// fused GEMM1 (BK=128, reg prefetch): [0,96): KK = Am@WkT + bk ; [96,288): rs_bf = ht@seqT
__global__ __launch_bounds__(256) void k_gemm1(
    const __hip_bfloat16* __restrict__ Ambf, const __hip_bfloat16* __restrict__ WkT,
    const float* __restrict__ bk, float* __restrict__ KK,
    const __hip_bfloat16* __restrict__ ht_bf, const __hip_bfloat16* __restrict__ seqT,
    __hip_bfloat16* __restrict__ rs_bf){
  __shared__ short As[64][136];
  __shared__ short Bs[64][136];
  const int tid = threadIdx.x;
  const int w = tid>>6, l = tid&63, wm = w>>1, wn = w&1;
  const int srow = tid>>4, sk8 = (tid&15)*8;
  const short *Ap, *Bp;
  int lda, ldb, K, bm, bn;
  bool isKK;
  if (blockIdx.x < 96){
    isKK = true;
    bm = (blockIdx.x/12)*64; bn = (blockIdx.x%12)*64;
    Ap = (const short*)Ambf + (size_t)bm*D_; lda = D_; K = D_;
    Bp = (const short*)WkT + (size_t)bn*D_;  ldb = D_;
  } else {
    isKK = false;
    const int z = blockIdx.x - 96;
    const int n = z/48, rem = z%48, bmI = rem/12, bnI = rem%12;
    bm = n*P_ + bmI*64; bn = bnI*64;
    Ap = (const short*)ht_bf + (size_t)bm*C_;            lda = C_;     K = C_;
    Bp = (const short*)seqT + (size_t)bn*(N_*C_) + n*C_; ldb = N_*C_;
  }
  short8 pA[4], pB[4];
  auto loadAB = [&](int k0){
    #pragma unroll
    for (int t=0;t<4;t++){
      const int row = srow + t*16;
      pA[t] = *(const short8*)&Ap[(size_t)row*lda + k0 + sk8];
      pB[t] = *(const short8*)&Bp[(size_t)row*ldb + k0 + sk8];
    }
  };
  loadAB(0);
  f32x4 acc[2][2] = {};
  for (int k0=0;k0<K;k0+=128){
    #pragma unroll
    for (int t=0;t<4;t++){
      *(short8*)&As[srow+t*16][sk8] = pA[t];
      *(short8*)&Bs[srow+t*16][sk8] = pB[t];
    }
    __syncthreads();
    if (k0+128 < K) loadAB(k0+128);
    #pragma unroll
    for (int h=0;h<4;h++){
      short8 af[2], bfv[2];
      #pragma unroll
      for (int f=0;f<2;f++){
        af[f]  = *(short8*)&As[wm*32+f*16+(l&15)][h*32+(l>>4)*8];
        bfv[f] = *(short8*)&Bs[wn*32+f*16+(l&15)][h*32+(l>>4)*8];
      }
      #pragma unroll
      for (int i=0;i<2;i++)
        #pragma unroll
        for (int j=0;j<2;j++)
          acc[i][j] = __builtin_amdgcn_mfma_f32_16x16x32_bf16(af[i], bfv[j], acc[i][j], 0,0,0);
    }
    __syncthreads();
  }
  #pragma unroll
  for (int i=0;i<2;i++)
    #pragma unroll
    for (int j=0;j<2;j++)
      #pragma unroll
      for (int r_=0;r_<4;r_++){
        const int row = bm + wm*32 + i*16 + (l>>4)*4 + r_;
        const int col = bn + wn*32 + j*16 + (l&15);
        const float v = acc[i][j][r_];
        if (isKK) KK[(size_t)row*D_ + col] = v + bk[col];
        else      rs_bf[(size_t)row*D_ + col] = __float2bfloat16(v);
      }
}

// qdot + softmax (precomputed kdot) + blend; also out = bb (bias init for bilinear atomics)
__global__ __launch_bounds__(256) void k_mention(
    const __hip_bfloat16* __restrict__ rs_bf, const float* __restrict__ KK,
    const float* __restrict__ vq, const float* __restrict__ qc2,
    const float* __restrict__ kdot, const int* __restrict__ pos,
    const int* __restrict__ hts,
    __hip_bfloat16* __restrict__ hess, __hip_bfloat16* __restrict__ tess,
    const float* __restrict__ bb, float* __restrict__ out){
  const int r = blockIdx.x, n = r>>8, tid = threadIdx.x;
  // init output row with bias (bilinear atomicAdds on top)
  if (tid < NL_) out[(size_t)r*NL_ + tid] = bb[tid];
  const unsigned short* rsp = (const unsigned short*)rs_bf + (size_t)r*D_;
  float s = 0.f;
  for (int d=tid; d<D_; d+=256) s += bf2f(rsp[d])*vq[d];
  const float q = blockReduceSum256(s) + qc2[0];
  #pragma unroll
  for (int side=0;side<2;side++){
    const int e = hts[r*2+side];
    const int base = (n*E_+e)*M_;
    float sc[4];
    #pragma unroll
    for (int m=0;m<4;m++){
      float t = q + kdot[base+m];
      t = (t > 0.f) ? t : 0.01f*t;
      sc[m] = (pos[base+m] != 0) ? t : -1e9f;
    }
    const float mx = fmaxf(fmaxf(sc[0],sc[1]), fmaxf(sc[2],sc[3]));
    float ex[4]; float sum = 0.f;
    #pragma unroll
    for (int m=0;m<4;m++){ ex[m] = expf(sc[m]-mx); sum += ex[m]; }
    const float inv = 1.f/sum;
    const float p0=ex[0]*inv, p1=ex[1]*inv, p2=ex[2]*inv, p3=ex[3]*inv;
    const float* K0 = KK + (size_t)(base+0)*D_;
    const float* K1 = KK + (size_t)(base+1)*D_;
    const float* K2 = KK + (size_t)(base+2)*D_;
    const float* K3 = KK + (size_t)(base+3)*D_;
    __hip_bfloat16* outp = (side ? tess : hess) + (size_t)r*D_;
    for (int d=tid; d<D_; d+=256)
      outp[d] = __float2bfloat16(p0*K0[d] + p1*K1[d] + p2*K2[d] + p3*K3[d]);
  }
}

// z GEMM split-K: blockIdx.z = ks*2 + side, ks in {0,1,2} selects the 768-chunk
// chunk boundaries align with [rs|ent|hx] concat regions. No bias/tanh here.
// zp layout: [(side*3+ks)][NP_][D_] f32 raw partial sums.
__global__ __launch_bounds__(256) void k_gemm_z(
    const __hip_bfloat16* __restrict__ rs_bf, const __hip_bfloat16* __restrict__ ent_bf,
    const __hip_bfloat16* __restrict__ hess_bf, const __hip_bfloat16* __restrict__ tess_bf,
    const int* __restrict__ hts,
    const __hip_bfloat16* __restrict__ WhT, const __hip_bfloat16* __restrict__ WtT,
    float* __restrict__ zp){
  const int side = blockIdx.z & 1;
  const int ks = blockIdx.z >> 1;
  const int bm = blockIdx.y*64, bn = blockIdx.x*64;
  const short* BT = (const short*)(side ? WtT : WhT);
  const short* hx  = (const short*)(side ? tess_bf : hess_bf);
  const short* rsp = (const short*)rs_bf;
  const short* enp = (const short*)ent_bf;
  float* Cm = zp + (size_t)(side*3 + ks)*NP_*D_;
  __shared__ short As[64][136];
  __shared__ short Bs[64][136];
  __shared__ int e_s[64];
  const int tid = threadIdx.x;
  if (tid < 64) e_s[tid] = hts[(bm+tid)*2 + side];
  __syncthreads();
  const int w = tid>>6, l = tid&63, wm = w>>1, wn = w&1;
  const int srow = tid>>4, sk8 = (tid&15)*8;
  short8 pA[4], pB[4];
  auto loadAB = [&](int k0){
    #pragma unroll
    for (int t=0;t<4;t++){
      const int row = srow + t*16;
      const int arow = bm + row;
      const int gk = k0 + sk8;               // 0..767 within chunk
      const short* src;
      if (ks == 0)      src = &rsp[(size_t)arow*D_ + gk];
      else if (ks == 1) src = &enp[((size_t)(arow>>8)*E_ + e_s[row])*D_ + gk];
      else              src = &hx[(size_t)arow*D_ + gk];
      pA[t] = *(const short8*)src;
      pB[t] = *(const short8*)&BT[(size_t)(bn+row)*K3D_ + ks*D_ + gk];
    }
  };
  loadAB(0);
  f32x4 acc[2][2] = {};
  for (int k0=0;k0<D_;k0+=128){
    #pragma unroll
    for (int t=0;t<4;t++){
      *(short8*)&As[srow+t*16][sk8] = pA[t];
      *(short8*)&Bs[srow+t*16][sk8] = pB[t];
    }
    __syncthreads();
    if (k0+128 < D_) loadAB(k0+128);
    #pragma unroll
    for (int h=0;h<4;h++){
      short8 af[2], bfv[2];
      #pragma unroll
      for (int f=0;f<2;f++){
        af[f]  = *(short8*)&As[wm*32+f*16+(l&15)][h*32+(l>>4)*8];
        bfv[f] = *(short8*)&Bs[wn*32+f*16+(l&15)][h*32+(l>>4)*8];
      }
      #pragma unroll
      for (int i=0;i<2;i++)
        #pragma unroll
        for (int j=0;j<2;j++)
          acc[i][j] = __builtin_amdgcn_mfma_f32_16x16x32_bf16(af[i], bfv[j], acc[i][j], 0,0,0);
    }
    __syncthreads();
  }
  #pragma unroll
  for (int i=0;i<2;i++)
    #pragma unroll
    for (int j=0;j<2;j++)
      #pragma unroll
      for (int r_=0;r_<4;r_++){
        const int row = bm + wm*32 + i*16 + (l>>4)*4 + r_;
        const int col = bn + wn*32 + j*16 + (l&15);
        Cm[(size_t)row*D_ + col] = acc[i][j][r_];
      }
}

// bilinear MFMA: z-partials summed + bias + tanh on LDS staging; atomicAdd into out
__global__ __launch_bounds__(256) void k_bilinear(
    const float* __restrict__ zp,
    const float* __restrict__ bh, const float* __restrict__ bt,
    const __hip_bfloat16* __restrict__ WbT, float* __restrict__ out){
  const int kc = blockIdx.x;          // 0..23
  const int blkI = kc >> 1, half = kc & 1;
  const int r0 = blockIdx.y*64;
  __shared__ float zh_s[64][36];
  __shared__ float zt_s[64][68];
  __shared__ short Bs[4][NLP_][40];
  const int tid = threadIdx.x;
  const size_t S = (size_t)NP_*D_;
  const float* zph = zp;              // side 0 partials: 0,S,2S
  const float* zpt = zp + 3*S;        // side 1 partials
  for (int idx=tid; idx<64*32; idx+=256){
    const int row = idx>>5, c = idx&31;
    const int col = blkI*64 + half*32 + c;
    const size_t o = (size_t)(r0+row)*D_ + col;
    float s = zph[o] + zph[S+o] + zph[2*S+o] + bh[col];
    s = tanhf(tanhf(s));
    zh_s[row][c] = s;
  }
  for (int idx=tid; idx<64*64; idx+=256){
    const int row = idx>>6, c = idx&63;
    const int col = blkI*64 + c;
    const size_t o = (size_t)(r0+row)*D_ + col;
    float s = zpt[o] + zpt[S+o] + zpt[2*S+o] + bt[col];
    zt_s[row][c] = tanhf(s);
  }
  const int w = tid>>6, l = tid&63;
  const int arow = w*16 + (l&15);
  const short* WT = (const short*)WbT;
  const size_t kbase = (size_t)blkI*4096 + half*2048;
  int sl[7], cl[7], k8l[7];
  #pragma unroll
  for (int t=0;t<7;t++){
    const int ci = tid + t*256;
    sl[t] = ci/448;
    const int rem = ci - sl[t]*448;
    cl[t] = rem>>2; k8l[t] = (rem&3)*8;
  }
  short8 pre[7];
  #pragma unroll
  for (int t=0;t<7;t++)
    pre[t] = *(const short8*)&WT[(size_t)cl[t]*KBL_ + kbase + (size_t)sl[t]*32 + k8l[t]];
  f32x4 acc[7] = {};
  for (int g=0; g<16; ++g){
    __syncthreads();
    #pragma unroll
    for (int t=0;t<7;t++) *(short8*)&Bs[sl[t]][cl[t]][k8l[t]] = pre[t];
    __syncthreads();
    if (g < 15){
      #pragma unroll
      for (int t=0;t<7;t++)
        pre[t] = *(const short8*)&WT[(size_t)cl[t]*KBL_ + kbase + (size_t)((g+1)*4+sl[t])*32 + k8l[t]];
    }
    #pragma unroll
    for (int ss=0;ss<4;ss++){
      const int s = g*4 + ss;
      const int iLoc = s>>1;
      const int jj = (s&1)*32 + (l>>4)*8;
      const float a = zh_s[arow][iLoc];
      f32x4 z0 = *(f32x4*)&zt_s[arow][jj];
      f32x4 z1 = *(f32x4*)&zt_s[arow][jj+4];
      short8 afr;
      #pragma unroll
      for (int t=0;t<4;t++) afr[t]   = f2bf(a*z0[t]);
      #pragma unroll
      for (int t=0;t<4;t++) afr[4+t] = f2bf(a*z1[t]);
      #pragma unroll
      for (int nf=0;nf<7;nf++){
        const short8 bfr = *(short8*)&Bs[ss][nf*16 + (l&15)][(l>>4)*8];
        acc[nf] = __builtin_amdgcn_mfma_f32_16x16x32_bf16(afr, bfr, acc[nf], 0,0,0);
      }
    }
  }
  #pragma unroll
  for (int nf=0;nf<7;nf++)
    #pragma unroll
    for (int r_=0;r_<4;r_++){
      const int row = r0 + w*16 + (l>>4)*4 + r_;
      const int col = nf*16 + (l&15);
      if (col < NL_)
        atomicAdd(&out[(size_t)row*NL_ + col], acc[nf][r_]);
    }
}

extern "C" void kernel_launch(void* const* d_in, const int* in_sizes, int n_in,
                              void* d_out, int out_size, void* d_ws, size_t ws_size,
                              hipStream_t stream){
  const float* seq  = (const float*)d_in[0];
  const float* attn = (const float*)d_in[1];
  const int*   pos  = (const int*)d_in[2];
  const int*   hts  = (const int*)d_in[3];
  const float* Wq = (const float*)d_in[4];
  const float* bq = (const float*)d_in[5];
  const float* Wk = (const float*)d_in[6];
  const float* bk = (const float*)d_in[7];
  const float* aw = (const float*)d_in[8];
  const float* ab = (const float*)d_in[9];
  const float* Wh = (const float*)d_in[10];
  const float* bh = (const float*)d_in[11];
  const float* Wt = (const float*)d_in[12];
  const float* bt = (const float*)d_in[13];
  const float* Wb = (const float*)d_in[14];
  const float* bb = (const float*)d_in[15];
  float* out = (float*)d_out;

  char* base = (char*)d_ws;
  size_t off = 0;
  auto alloc = [&](size_t bytes)->void*{
    void* p = base + off;
    off += (bytes + 255) & ~(size_t)255;
    return p;
  };
  __hip_bfloat16* WhT   = (__hip_bfloat16*)alloc((size_t)D_*K3D_*2);
  __hip_bfloat16* WtT   = (__hip_bfloat16*)alloc((size_t)D_*K3D_*2);
  __hip_bfloat16* WkT   = (__hip_bfloat16*)alloc((size_t)D_*D_*2);
  __hip_bfloat16* WbT   = (__hip_bfloat16*)alloc((size_t)NLP_*KBL_*2);
  __hip_bfloat16* seqT  = (__hip_bfloat16*)alloc((size_t)D_*N_*C_*2);
  __hip_bfloat16* ent_bf= (__hip_bfloat16*)alloc((size_t)N_*E_*D_*2);
  __hip_bfloat16* att_bf= (__hip_bfloat16*)alloc((size_t)N_*E_*H_*C_*2);
  __hip_bfloat16* ht_bf = (__hip_bfloat16*)alloc((size_t)NP_*C_*2);
  __hip_bfloat16* Ambf  = (__hip_bfloat16*)alloc((size_t)N_*E_*M_*D_*2);
  float* KK             = (float*)alloc((size_t)N_*E_*M_*D_*4);
  float* vq             = (float*)alloc(D_*4);
  float* wk_aw          = (float*)alloc(D_*4);
  float* qc2            = (float*)alloc(256);
  float* kdot           = (float*)alloc(512*4);
  __hip_bfloat16* rs_bf = (__hip_bfloat16*)alloc((size_t)NP_*D_*2);
  __hip_bfloat16* hess  = (__hip_bfloat16*)alloc((size_t)NP_*D_*2);
  __hip_bfloat16* tess  = (__hip_bfloat16*)alloc((size_t)NP_*D_*2);
  float* zp             = (float*)alloc((size_t)6*NP_*D_*4);
  (void)ws_size; (void)in_sizes; (void)n_in; (void)out_size;

  k_prep<<<G_PREP, 256, 0, stream>>>(seq, attn, pos, Wq, bq, Wk, bk, aw, ab, Wh, Wt, Wb,
                                     WhT, WtT, WkT, WbT, seqT, ent_bf, Ambf, att_bf,
                                     vq, wk_aw, qc2);
  k_ht2<<<NP_ + 512, 256, 0, stream>>>(att_bf, hts, Ambf, wk_aw, qc2, ht_bf, kdot);
  k_gemm1<<<288, 256, 0, stream>>>(Ambf, WkT, bk, KK, ht_bf, seqT, rs_bf);
  k_mention<<<NP_, 256, 0, stream>>>(rs_bf, KK, vq, qc2, kdot, pos, hts, hess, tess, bb, out);
  k_gemm_z<<<dim3(D_/64, NP_/64, 6), 256, 0, stream>>>(rs_bf, ent_bf, hess, tess, hts,
                                                       WhT, WtT, zp);
  k_bilinear<<<dim3(24, NP_/64), 256, 0, stream>>>(zp, bh, bt, WbT, out);
}

// Round 7
// 104.326 us; speedup vs baseline: 1.1240x; 1.1240x over previous
//
#include <hip/hip_runtime.h>
#include <hip/hip_bf16.h>
#include <math.h>

#define N_ 4
#define C_ 1024
#define D_ 768
#define H_ 12
#define E_ 32
#define M_ 4
#define P_ 256
#define NL_ 97
#define NLP_ 112
#define NP_ (N_*P_)
#define K3D_ 2304
#define KBL_ 49152

typedef __attribute__((ext_vector_type(8))) short short8;
typedef __attribute__((ext_vector_type(4))) float f32x4;
typedef __attribute__((ext_vector_type(4))) unsigned short ushort4v;

__device__ __forceinline__ short f2bf(float x){
  union { __hip_bfloat16 h; short s; } u; u.h = __float2bfloat16(x); return u.s;
}
__device__ __forceinline__ unsigned short f2bfu(float x){
  union { __hip_bfloat16 h; unsigned short s; } u; u.h = __float2bfloat16(x); return u.s;
}
__device__ __forceinline__ float bf2f(unsigned short u){
  union { unsigned int i; float f; } x; x.i = ((unsigned int)u)<<16; return x.f;
}

__device__ __forceinline__ float blockReduceSum256(float v){
  __shared__ float red_s[4];
  #pragma unroll
  for (int o=32;o>0;o>>=1) v += __shfl_down(v, o);
  if ((threadIdx.x & 63)==0) red_s[threadIdx.x>>6] = v;
  __syncthreads();
  float t = red_s[0]+red_s[1]+red_s[2]+red_s[3];
  __syncthreads();
  return t;
}

// transpose+cvt 64(R)x32(C) tile: in [R][C] f32 -> out [Cp][R] bf16, zero-pad c>=C
__device__ __forceinline__ void tcvt64(const float* __restrict__ in,
    __hip_bfloat16* __restrict__ out, int R, int C, int Cp, int tile){
  __shared__ float tb[64][33];
  const int tiles_c = (Cp + 31) >> 5;
  const int rb = (tile/tiles_c)*64, cb = (tile%tiles_c)*32;
  const int tid = threadIdx.x;
  const bool vec = ((C & 3) == 0);
  #pragma unroll
  for (int i=0;i<2;i++){
    const int idx = tid + i*256;
    const int row = idx>>3, c4 = (idx&7)*4;
    const int c = cb + c4;
    float v0=0.f,v1=0.f,v2=0.f,v3=0.f;
    if (vec && c+3 < C){
      const f32x4 v = *(const f32x4*)&in[(size_t)(rb+row)*C + c];
      v0=v[0]; v1=v[1]; v2=v[2]; v3=v[3];
    } else {
      const float* rp = in + (size_t)(rb+row)*C;
      if (c   < C) v0 = rp[c];
      if (c+1 < C) v1 = rp[c+1];
      if (c+2 < C) v2 = rp[c+2];
      if (c+3 < C) v3 = rp[c+3];
    }
    tb[row][c4]=v0; tb[row][c4+1]=v1; tb[row][c4+2]=v2; tb[row][c4+3]=v3;
  }
  __syncthreads();
  #pragma unroll
  for (int i=0;i<4;i++){
    const int idx = tid + i*256;
    const int cr = idx>>5, p = idx&31;
    const int cc = cb + cr;
    if (cc < Cp){
      union { struct { unsigned short a,b; } s; unsigned int u; } pk;
      pk.s.a = f2bfu(tb[2*p][cr]);
      pk.s.b = f2bfu(tb[2*p+1][cr]);
      *(unsigned int*)&out[(size_t)cc*R + rb + 2*p] = pk.u;
    }
  }
}

// prep block ranges
#define T_WH 864            // (2304/64)*24
#define T_WT 864
#define T_WK 288            // (768/64)*24
#define T_WB 3072           // (49152/64)*4   (ceil(112/32)=4)
#define T_SEQ 1536          // (4096/64)*24
#define O_WT  (T_WH)
#define O_WK  (O_WT+T_WT)
#define O_WB  (O_WK+T_WK)
#define O_SEQ (O_WB+T_WB)
#define O_EMB (O_SEQ+T_SEQ)
#define O_ATT (O_EMB+N_*E_)
#define O_VQ  (O_ATT+N_*E_*H_)
#define O_WKAW (O_VQ+D_)
#define O_MISC (O_WKAW+D_)
#define G_PREP (O_MISC+1)

__global__ __launch_bounds__(256) void k_prep(
    const float* __restrict__ seq, const float* __restrict__ attn,
    const int* __restrict__ pos,
    const float* __restrict__ Wq, const float* __restrict__ bq,
    const float* __restrict__ Wk, const float* __restrict__ bk,
    const float* __restrict__ aw, const float* __restrict__ ab,
    const float* __restrict__ Wh, const float* __restrict__ Wt,
    const float* __restrict__ Wb,
    __hip_bfloat16* __restrict__ WhT, __hip_bfloat16* __restrict__ WtT,
    __hip_bfloat16* __restrict__ WkT, __hip_bfloat16* __restrict__ WbT,
    __hip_bfloat16* __restrict__ seqT,
    __hip_bfloat16* __restrict__ ent_bf, __hip_bfloat16* __restrict__ Ambf,
    __hip_bfloat16* __restrict__ att_bf,
    float* __restrict__ vq, float* __restrict__ wk_aw, float* __restrict__ qc2){
  const int b = blockIdx.x;
  const int tid = threadIdx.x;
  if (b < O_WT){ tcvt64(Wh, WhT, K3D_, D_, D_, b); return; }
  if (b < O_WK){ tcvt64(Wt, WtT, K3D_, D_, D_, b-O_WT); return; }
  if (b < O_WB){ tcvt64(Wk, WkT, D_, D_, D_, b-O_WK); return; }
  if (b < O_SEQ){ tcvt64(Wb, WbT, KBL_, NL_, NLP_, b-O_WB); return; }
  if (b < O_EMB){ tcvt64(seq, seqT, N_*C_, D_, D_, b-O_SEQ); return; }
  if (b < O_ATT){
    const int be = b - O_EMB;
    const int n = be >> 5;
    const int* pp = pos + be*M_;
    if (tid < 192){
      const int c4 = tid*4;
      const f32x4 v0 = *(const f32x4*)&seq[((size_t)n*C_ + pp[0])*D_ + c4];
      const f32x4 v1 = *(const f32x4*)&seq[((size_t)n*C_ + pp[1])*D_ + c4];
      const f32x4 v2 = *(const f32x4*)&seq[((size_t)n*C_ + pp[2])*D_ + c4];
      const f32x4 v3 = *(const f32x4*)&seq[((size_t)n*C_ + pp[3])*D_ + c4];
      ushort4v a0,a1,a2,a3,e;
      #pragma unroll
      for (int j=0;j<4;j++){
        a0[j]=f2bfu(v0[j]); a1[j]=f2bfu(v1[j]); a2[j]=f2bfu(v2[j]); a3[j]=f2bfu(v3[j]);
        const float m = fmaxf(fmaxf(v0[j],v1[j]), fmaxf(v2[j],v3[j]));
        const float s = expf(v0[j]-m)+expf(v1[j]-m)+expf(v2[j]-m)+expf(v3[j]-m);
        e[j] = f2bfu(m + logf(s));
      }
      *(ushort4v*)&Ambf[(size_t)(be*4+0)*D_ + c4] = a0;
      *(ushort4v*)&Ambf[(size_t)(be*4+1)*D_ + c4] = a1;
      *(ushort4v*)&Ambf[(size_t)(be*4+2)*D_ + c4] = a2;
      *(ushort4v*)&Ambf[(size_t)(be*4+3)*D_ + c4] = a3;
      *(ushort4v*)&ent_bf[(size_t)be*D_ + c4] = e;
    }
    return;
  }
  if (b < O_VQ){
    const int bb2 = b - O_ATT;          // (n*E+e)*H + h
    const int h = bb2 % H_;
    const int ne = bb2 / H_;
    const int n = ne >> 5;
    const int* pp = pos + ne*M_;
    const float* basep = attn + ((size_t)(n*H_+h))*C_*C_;
    const int c4 = tid*4;
    const f32x4 r0 = *(const f32x4*)&basep[(size_t)pp[0]*C_ + c4];
    const f32x4 r1 = *(const f32x4*)&basep[(size_t)pp[1]*C_ + c4];
    const f32x4 r2 = *(const f32x4*)&basep[(size_t)pp[2]*C_ + c4];
    const f32x4 r3 = *(const f32x4*)&basep[(size_t)pp[3]*C_ + c4];
    ushort4v o;
    #pragma unroll
    for (int j=0;j<4;j++) o[j] = f2bfu(0.25f*(r0[j]+r1[j]+r2[j]+r3[j]));
    *(ushort4v*)&att_bf[(size_t)bb2*C_ + c4] = o;
    return;
  }
  if (b < O_WKAW){
    const int k = b - O_VQ;
    float s = 0.f;
    for (int d=tid; d<D_; d+=256) s += Wq[(size_t)k*D_+d]*aw[d];
    s = blockReduceSum256(s);
    if (tid==0) vq[k] = s;
    return;
  }
  if (b < O_MISC){
    const int k = b - O_WKAW;
    float s = 0.f;
    for (int d=tid; d<D_; d+=256) s += Wk[(size_t)k*D_+d]*aw[D_+d];
    s = blockReduceSum256(s);
    if (tid==0) wk_aw[k] = s;
    return;
  }
  {
    float s0 = 0.f, s1 = 0.f;
    for (int d=tid; d<D_; d+=256){ s0 += bq[d]*aw[d]; s1 += bk[d]*aw[D_+d]; }
    s0 = blockReduceSum256(s0);
    s1 = blockReduceSum256(s1);
    if (tid==0){ qc2[0] = s0 + ab[0]; qc2[1] = s1; }
  }
}

// ht_att (bf16 in/out) + kdot[512]
__global__ __launch_bounds__(256) void k_ht2(
    const __hip_bfloat16* __restrict__ att_bf, const int* __restrict__ hts,
    const __hip_bfloat16* __restrict__ Ambf, const float* __restrict__ wk_aw,
    const float* __restrict__ qc2,
    __hip_bfloat16* __restrict__ ht_bf, float* __restrict__ kdot){
  const int b = blockIdx.x, tid = threadIdx.x;
  if (b < NP_){
    const int r = b, n = r >> 8;
    const int he = hts[r*2], te = hts[r*2+1];
    const unsigned short* ha = (const unsigned short*)att_bf + ((size_t)(n*E_+he))*H_*C_;
    const unsigned short* ta = (const unsigned short*)att_bf + ((size_t)(n*E_+te))*H_*C_;
    const int c0 = tid*4;
    float v[4] = {0.f,0.f,0.f,0.f};
    #pragma unroll
    for (int h=0;h<H_;h++){
      const ushort4v a = *(const ushort4v*)&ha[h*C_ + c0];
      const ushort4v t = *(const ushort4v*)&ta[h*C_ + c0];
      #pragma unroll
      for (int j=0;j<4;j++) v[j] = fmaf(bf2f(a[j]), bf2f(t[j]), v[j]);
    }
    float local = 0.f;
    #pragma unroll
    for (int j=0;j<4;j++){ v[j] *= (1.0f/H_); local += v[j]; }
    const float tot = blockReduceSum256(local);
    const float inv = 1.f/(tot + 1e-5f);
    ushort4v o;
    #pragma unroll
    for (int j=0;j<4;j++) o[j] = f2bfu(v[j]*inv);
    *(ushort4v*)&ht_bf[(size_t)r*C_ + c0] = o;
  } else {
    const int g = b - NP_;           // 0..511
    const unsigned short* Am = (const unsigned short*)Ambf + (size_t)g*D_;
    float s = 0.f;
    for (int d=tid; d<D_; d+=256) s += bf2f(Am[d])*wk_aw[d];
    s = blockReduceSum256(s);
    if (tid==0) kdot[g] = s + qc2[1];
  }
}

// fused GEMM1 (BK=128, reg prefetch), XCD-chunked block remap:
// work: [0,96): KK = Am@WkT + bk ; [96,288): rs_bf = ht@seqT
__global__ __launch_bounds__(256) void k_gemm1(
    const __hip_bfloat16* __restrict__ Ambf, const __hip_bfloat16* __restrict__ WkT,
    const float* __restrict__ bk, float* __restrict__ KK,
    const __hip_bfloat16* __restrict__ ht_bf, const __hip_bfloat16* __restrict__ seqT,
    __hip_bfloat16* __restrict__ rs_bf){
  __shared__ short As[64][136];
  __shared__ short Bs[64][136];
  const int tid = threadIdx.x;
  const int w = tid>>6, l = tid&63, wm = w>>1, wn = w&1;
  const int srow = tid>>4, sk8 = (tid&15)*8;
  // T1 swizzle: 288 blocks = 36/XCD contiguous works -> B-slice L2 locality
  const int p = blockIdx.x;
  const int work = (p & 7)*36 + (p >> 3);
  const short *Ap, *Bp;
  int lda, ldb, K, bm, bn;
  bool isKK;
  if (work < 96){
    isKK = true;
    bm = (work/12)*64; bn = (work%12)*64;
    Ap = (const short*)Ambf + (size_t)bm*D_; lda = D_; K = D_;
    Bp = (const short*)WkT + (size_t)bn*D_;  ldb = D_;
  } else {
    isKK = false;
    const int z = work - 96;
    const int n = z/48, rem = z%48, bnI = rem/16, bmI = rem%16;  // group by (n,bn): 4 blocks share B slice? 16 bm per (n,bnI)
    bm = n*P_ + (bmI&3)*64; bn = (bnI*4 + (bmI>>2))*64;
    Ap = (const short*)ht_bf + (size_t)bm*C_;            lda = C_;     K = C_;
    Bp = (const short*)seqT + (size_t)bn*(N_*C_) + n*C_; ldb = N_*C_;
  }
  short8 pA[4], pB[4];
  auto loadAB = [&](int k0){
    #pragma unroll
    for (int t=0;t<4;t++){
      const int row = srow + t*16;
      pA[t] = *(const short8*)&Ap[(size_t)row*lda + k0 + sk8];
      pB[t] = *(const short8*)&Bp[(size_t)row*ldb + k0 + sk8];
    }
  };
  loadAB(0);
  f32x4 acc[2][2] = {};
  for (int k0=0;k0<K;k0+=128){
    #pragma unroll
    for (int t=0;t<4;t++){
      *(short8*)&As[srow+t*16][sk8] = pA[t];
      *(short8*)&Bs[srow+t*16][sk8] = pB[t];
    }
    __syncthreads();
    if (k0+128 < K) loadAB(k0+128);
    #pragma unroll
    for (int h=0;h<4;h++){
      short8 af[2], bfv[2];
      #pragma unroll
      for (int f=0;f<2;f++){
        af[f]  = *(short8*)&As[wm*32+f*16+(l&15)][h*32+(l>>4)*8];
        bfv[f] = *(short8*)&Bs[wn*32+f*16+(l&15)][h*32+(l>>4)*8];
      }
      #pragma unroll
      for (int i=0;i<2;i++)
        #pragma unroll
        for (int j=0;j<2;j++)
          acc[i][j] = __builtin_amdgcn_mfma_f32_16x16x32_bf16(af[i], bfv[j], acc[i][j], 0,0,0);
    }
    __syncthreads();
  }
  #pragma unroll
  for (int i=0;i<2;i++)
    #pragma unroll
    for (int j=0;j<2;j++)
      #pragma unroll
      for (int r_=0;r_<4;r_++){
        const int row = bm + wm*32 + i*16 + (l>>4)*4 + r_;
        const int col = bn + wn*32 + j*16 + (l&15);
        const float v = acc[i][j][r_];
        if (isKK) KK[(size_t)row*D_ + col] = v + bk[col];
        else      rs_bf[(size_t)row*D_ + col] = __float2bfloat16(v);
      }
}

// qdot + softmax (precomputed kdot) + blend
__global__ __launch_bounds__(256) void k_mention(
    const __hip_bfloat16* __restrict__ rs_bf, const float* __restrict__ KK,
    const float* __restrict__ vq, const float* __restrict__ qc2,
    const float* __restrict__ kdot, const int* __restrict__ pos,
    const int* __restrict__ hts,
    __hip_bfloat16* __restrict__ hess, __hip_bfloat16* __restrict__ tess){
  const int r = blockIdx.x, n = r>>8, tid = threadIdx.x;
  const unsigned short* rsp = (const unsigned short*)rs_bf + (size_t)r*D_;
  float s = 0.f;
  for (int d=tid; d<D_; d+=256) s += bf2f(rsp[d])*vq[d];
  const float q = blockReduceSum256(s) + qc2[0];
  #pragma unroll
  for (int side=0;side<2;side++){
    const int e = hts[r*2+side];
    const int base = (n*E_+e)*M_;
    float sc[4];
    #pragma unroll
    for (int m=0;m<4;m++){
      float t = q + kdot[base+m];
      t = (t > 0.f) ? t : 0.01f*t;
      sc[m] = (pos[base+m] != 0) ? t : -1e9f;
    }
    const float mx = fmaxf(fmaxf(sc[0],sc[1]), fmaxf(sc[2],sc[3]));
    float ex[4]; float sum = 0.f;
    #pragma unroll
    for (int m=0;m<4;m++){ ex[m] = expf(sc[m]-mx); sum += ex[m]; }
    const float inv = 1.f/sum;
    const float p0=ex[0]*inv, p1=ex[1]*inv, p2=ex[2]*inv, p3=ex[3]*inv;
    const float* K0 = KK + (size_t)(base+0)*D_;
    const float* K1 = KK + (size_t)(base+1)*D_;
    const float* K2 = KK + (size_t)(base+2)*D_;
    const float* K3 = KK + (size_t)(base+3)*D_;
    __hip_bfloat16* outp = (side ? tess : hess) + (size_t)r*D_;
    for (int d=tid; d<D_; d+=256)
      outp[d] = __float2bfloat16(p0*K0[d] + p1*K1[d] + p2*K2[d] + p3*K3[d]);
  }
}

// z GEMM, BK=128, reg prefetch, gather-fused A, fused bias+tanh epilogue.
// 1D grid 384 with XCD-chunked remap: each XCD gets 3 full (side,bn) groups
// of 16 r0-blocks -> B slice (295KB x3) L2-resident per XCD.
__global__ __launch_bounds__(256) void k_gemm_z(
    const __hip_bfloat16* __restrict__ rs_bf, const __hip_bfloat16* __restrict__ ent_bf,
    const __hip_bfloat16* __restrict__ hess_bf, const __hip_bfloat16* __restrict__ tess_bf,
    const int* __restrict__ hts,
    const __hip_bfloat16* __restrict__ WhT, const __hip_bfloat16* __restrict__ WtT,
    const float* __restrict__ bh, const float* __restrict__ bt,
    float* __restrict__ zh, float* __restrict__ zt){
  const int p = blockIdx.x;
  const int work = (p & 7)*48 + (p >> 3);
  const int side = work / 192;
  const int w2 = work - side*192;
  const int bn = (w2 / 16)*64;
  const int bm = (w2 & 15)*64;
  const short* BT = (const short*)(side ? WtT : WhT);
  const float* bias = side ? bt : bh;
  float* Cm = side ? zt : zh;
  const short* hx  = (const short*)(side ? tess_bf : hess_bf);
  const short* rsp = (const short*)rs_bf;
  const short* enp = (const short*)ent_bf;
  __shared__ short As[64][136];
  __shared__ short Bs[64][136];
  __shared__ int e_s[64];
  const int tid = threadIdx.x;
  if (tid < 64) e_s[tid] = hts[(bm+tid)*2 + side];
  __syncthreads();
  const int w = tid>>6, l = tid&63, wm = w>>1, wn = w&1;
  const int srow = tid>>4, sk8 = (tid&15)*8;
  short8 pA[4], pB[4];
  auto loadAB = [&](int k0){
    #pragma unroll
    for (int t=0;t<4;t++){
      const int row = srow + t*16;
      const int arow = bm + row;
      const int gk = k0 + sk8;
      const short* src;
      if (gk < D_)        src = &rsp[(size_t)arow*D_ + gk];
      else if (gk < 2*D_) src = &enp[((size_t)(arow>>8)*E_ + e_s[row])*D_ + gk - D_];
      else                src = &hx[(size_t)arow*D_ + gk - 2*D_];
      pA[t] = *(const short8*)src;
      pB[t] = *(const short8*)&BT[(size_t)(bn+row)*K3D_ + gk];
    }
  };
  loadAB(0);
  f32x4 acc[2][2] = {};
  for (int k0=0;k0<K3D_;k0+=128){
    #pragma unroll
    for (int t=0;t<4;t++){
      *(short8*)&As[srow+t*16][sk8] = pA[t];
      *(short8*)&Bs[srow+t*16][sk8] = pB[t];
    }
    __syncthreads();
    if (k0+128 < K3D_) loadAB(k0+128);
    #pragma unroll
    for (int h=0;h<4;h++){
      short8 af[2], bfv[2];
      #pragma unroll
      for (int f=0;f<2;f++){
        af[f]  = *(short8*)&As[wm*32+f*16+(l&15)][h*32+(l>>4)*8];
        bfv[f] = *(short8*)&Bs[wn*32+f*16+(l&15)][h*32+(l>>4)*8];
      }
      #pragma unroll
      for (int i=0;i<2;i++)
        #pragma unroll
        for (int j=0;j<2;j++)
          acc[i][j] = __builtin_amdgcn_mfma_f32_16x16x32_bf16(af[i], bfv[j], acc[i][j], 0,0,0);
    }
    __syncthreads();
  }
  #pragma unroll
  for (int i=0;i<2;i++)
    #pragma unroll
    for (int j=0;j<2;j++)
      #pragma unroll
      for (int r_=0;r_<4;r_++){
        const int row = bm + wm*32 + i*16 + (l>>4)*4 + r_;
        const int col = bn + wn*32 + j*16 + (l&15);
        float v = acc[i][j][r_] + bias[col];
        v = tanhf(v);
        if (side==0) v = tanhf(v);
        Cm[(size_t)row*D_ + col] = v;
      }
}

// bilinear MFMA: bf16 partial out; 1D grid 384 with explicit same-kc->same-XCD remap
__global__ __launch_bounds__(256) void k_bilinear(
    const float* __restrict__ zh, const float* __restrict__ zt,
    const __hip_bfloat16* __restrict__ WbT, __hip_bfloat16* __restrict__ partial){
  const int p = blockIdx.x;
  const int work = (p & 7)*48 + (p >> 3);
  const int kc = work >> 4;           // 0..23, 3 per XCD
  const int r0 = (work & 15)*64;
  const int blkI = kc >> 1, half = kc & 1;
  __shared__ float zh_s[64][36];
  __shared__ float zt_s[64][68];
  __shared__ short Bs[4][NLP_][40];
  const int tid = threadIdx.x;
  for (int idx=tid; idx<64*32; idx+=256){
    const int row = idx>>5, c = idx&31;
    zh_s[row][c] = zh[(size_t)(r0+row)*D_ + blkI*64 + half*32 + c];
  }
  for (int idx=tid; idx<64*64; idx+=256){
    const int row = idx>>6, c = idx&63;
    zt_s[row][c] = zt[(size_t)(r0+row)*D_ + blkI*64 + c];
  }
  const int w = tid>>6, l = tid&63;
  const int arow = w*16 + (l&15);
  const short* WT = (const short*)WbT;
  const size_t kbase = (size_t)blkI*4096 + half*2048;
  int sl[7], cl[7], k8l[7];
  #pragma unroll
  for (int t=0;t<7;t++){
    const int ci = tid + t*256;
    sl[t] = ci/448;
    const int rem = ci - sl[t]*448;
    cl[t] = rem>>2; k8l[t] = (rem&3)*8;
  }
  short8 pre[7];
  #pragma unroll
  for (int t=0;t<7;t++)
    pre[t] = *(const short8*)&WT[(size_t)cl[t]*KBL_ + kbase + (size_t)sl[t]*32 + k8l[t]];
  f32x4 acc[7] = {};
  for (int g=0; g<16; ++g){
    __syncthreads();
    #pragma unroll
    for (int t=0;t<7;t++) *(short8*)&Bs[sl[t]][cl[t]][k8l[t]] = pre[t];
    __syncthreads();
    if (g < 15){
      #pragma unroll
      for (int t=0;t<7;t++)
        pre[t] = *(const short8*)&WT[(size_t)cl[t]*KBL_ + kbase + (size_t)((g+1)*4+sl[t])*32 + k8l[t]];
    }
    #pragma unroll
    for (int ss=0;ss<4;ss++){
      const int s = g*4 + ss;
      const int iLoc = s>>1;
      const int jj = (s&1)*32 + (l>>4)*8;
      const float a = zh_s[arow][iLoc];
      f32x4 z0 = *(f32x4*)&zt_s[arow][jj];
      f32x4 z1 = *(f32x4*)&zt_s[arow][jj+4];
      short8 afr;
      #pragma unroll
      for (int t=0;t<4;t++) afr[t]   = f2bf(a*z0[t]);
      #pragma unroll
      for (int t=0;t<4;t++) afr[4+t] = f2bf(a*z1[t]);
      #pragma unroll
      for (int nf=0;nf<7;nf++){
        const short8 bfr = *(short8*)&Bs[ss][nf*16 + (l&15)][(l>>4)*8];
        acc[nf] = __builtin_amdgcn_mfma_f32_16x16x32_bf16(afr, bfr, acc[nf], 0,0,0);
      }
    }
  }
  unsigned short* pp = (unsigned short*)partial;
  #pragma unroll
  for (int nf=0;nf<7;nf++)
    #pragma unroll
    for (int r_=0;r_<4;r_++){
      const int row = r0 + w*16 + (l>>4)*4 + r_;
      const int col = nf*16 + (l&15);
      pp[((size_t)kc*NP_ + row)*NLP_ + col] = f2bfu(acc[nf][r_]);
    }
}

__global__ __launch_bounds__(256) void k_reduce(const __hip_bfloat16* __restrict__ partial,
    const float* __restrict__ bb, float* __restrict__ out){
  const int idx = blockIdx.x*256 + threadIdx.x;
  if (idx >= NP_*NL_) return;
  const int r = idx / NL_;
  const int l = idx - r*NL_;
  const unsigned short* pp = (const unsigned short*)partial;
  float s = bb[l];
  #pragma unroll
  for (int kc=0;kc<24;kc++) s += bf2f(pp[((size_t)kc*NP_ + r)*NLP_ + l]);
  out[idx] = s;
}

extern "C" void kernel_launch(void* const* d_in, const int* in_sizes, int n_in,
                              void* d_out, int out_size, void* d_ws, size_t ws_size,
                              hipStream_t stream){
  const float* seq  = (const float*)d_in[0];
  const float* attn = (const float*)d_in[1];
  const int*   pos  = (const int*)d_in[2];
  const int*   hts  = (const int*)d_in[3];
  const float* Wq = (const float*)d_in[4];
  const float* bq = (const float*)d_in[5];
  const float* Wk = (const float*)d_in[6];
  const float* bk = (const float*)d_in[7];
  const float* aw = (const float*)d_in[8];
  const float* ab = (const float*)d_in[9];
  const float* Wh = (const float*)d_in[10];
  const float* bh = (const float*)d_in[11];
  const float* Wt = (const float*)d_in[12];
  const float* bt = (const float*)d_in[13];
  const float* Wb = (const float*)d_in[14];
  const float* bb = (const float*)d_in[15];
  float* out = (float*)d_out;

  char* base = (char*)d_ws;
  size_t off = 0;
  auto alloc = [&](size_t bytes)->void*{
    void* p = base + off;
    off += (bytes + 255) & ~(size_t)255;
    return p;
  };
  __hip_bfloat16* WhT   = (__hip_bfloat16*)alloc((size_t)D_*K3D_*2);
  __hip_bfloat16* WtT   = (__hip_bfloat16*)alloc((size_t)D_*K3D_*2);
  __hip_bfloat16* WkT   = (__hip_bfloat16*)alloc((size_t)D_*D_*2);
  __hip_bfloat16* WbT   = (__hip_bfloat16*)alloc((size_t)NLP_*KBL_*2);
  __hip_bfloat16* seqT  = (__hip_bfloat16*)alloc((size_t)D_*N_*C_*2);
  __hip_bfloat16* ent_bf= (__hip_bfloat16*)alloc((size_t)N_*E_*D_*2);
  __hip_bfloat16* att_bf= (__hip_bfloat16*)alloc((size_t)N_*E_*H_*C_*2);
  __hip_bfloat16* ht_bf = (__hip_bfloat16*)alloc((size_t)NP_*C_*2);
  __hip_bfloat16* Ambf  = (__hip_bfloat16*)alloc((size_t)N_*E_*M_*D_*2);
  float* KK             = (float*)alloc((size_t)N_*E_*M_*D_*4);
  float* vq             = (float*)alloc(D_*4);
  float* wk_aw          = (float*)alloc(D_*4);
  float* qc2            = (float*)alloc(256);
  float* kdot           = (float*)alloc(512*4);
  __hip_bfloat16* rs_bf = (__hip_bfloat16*)alloc((size_t)NP_*D_*2);
  __hip_bfloat16* hess  = (__hip_bfloat16*)alloc((size_t)NP_*D_*2);
  __hip_bfloat16* tess  = (__hip_bfloat16*)alloc((size_t)NP_*D_*2);
  float* zh             = (float*)alloc((size_t)NP_*D_*4);
  float* zt             = (float*)alloc((size_t)NP_*D_*4);
  __hip_bfloat16* partial = (__hip_bfloat16*)alloc((size_t)24*NP_*NLP_*2);
  (void)ws_size; (void)in_sizes; (void)n_in; (void)out_size;

  k_prep<<<G_PREP, 256, 0, stream>>>(seq, attn, pos, Wq, bq, Wk, bk, aw, ab, Wh, Wt, Wb,
                                     WhT, WtT, WkT, WbT, seqT, ent_bf, Ambf, att_bf,
                                     vq, wk_aw, qc2);
  k_ht2<<<NP_ + 512, 256, 0, stream>>>(att_bf, hts, Ambf, wk_aw, qc2, ht_bf, kdot);
  k_gemm1<<<288, 256, 0, stream>>>(Ambf, WkT, bk, KK, ht_bf, seqT, rs_bf);
  k_mention<<<NP_, 256, 0, stream>>>(rs_bf, KK, vq, qc2, kdot, pos, hts, hess, tess);
  k_gemm_z<<<384, 256, 0, stream>>>(rs_bf, ent_bf, hess, tess, hts,
                                    WhT, WtT, bh, bt, zh, zt);
  k_bilinear<<<384, 256, 0, stream>>>(zh, zt, WbT, partial);
  k_reduce<<<(NP_*NL_+255)/256, 256, 0, stream>>>(partial, bb, out);
}

// Round 8
// 103.814 us; speedup vs baseline: 1.1296x; 1.0049x over previous
//
#include <hip/hip_runtime.h>
#include <hip/hip_bf16.h>
#include <math.h>

#define N_ 4
#define C_ 1024
#define D_ 768
#define H_ 12
#define E_ 32
#define M_ 4
#define P_ 256
#define NL_ 97
#define NLP_ 112
#define NP_ (N_*P_)
#define K3D_ 2304
#define KBL_ 49152

typedef __attribute__((ext_vector_type(8))) short short8;
typedef __attribute__((ext_vector_type(4))) float f32x4;
typedef __attribute__((ext_vector_type(4))) unsigned short ushort4v;

#define GLOAD_LDS16(g, l) __builtin_amdgcn_global_load_lds( \
    (const __attribute__((address_space(1))) void*)(g), \
    (__attribute__((address_space(3))) void*)(l), 16, 0, 0)

__device__ __forceinline__ short f2bf(float x){
  union { __hip_bfloat16 h; short s; } u; u.h = __float2bfloat16(x); return u.s;
}
__device__ __forceinline__ unsigned short f2bfu(float x){
  union { __hip_bfloat16 h; unsigned short s; } u; u.h = __float2bfloat16(x); return u.s;
}
__device__ __forceinline__ float bf2f(unsigned short u){
  union { unsigned int i; float f; } x; x.i = ((unsigned int)u)<<16; return x.f;
}

__device__ __forceinline__ float blockReduceSum256(float v){
  __shared__ float red_s[4];
  #pragma unroll
  for (int o=32;o>0;o>>=1) v += __shfl_down(v, o);
  if ((threadIdx.x & 63)==0) red_s[threadIdx.x>>6] = v;
  __syncthreads();
  float t = red_s[0]+red_s[1]+red_s[2]+red_s[3];
  __syncthreads();
  return t;
}

// transpose+cvt 64(R)x32(C) tile: in [R][C] f32 -> out [Cp][R] bf16, zero-pad c>=C
__device__ __forceinline__ void tcvt64(const float* __restrict__ in,
    __hip_bfloat16* __restrict__ out, int R, int C, int Cp, int tile){
  __shared__ float tb[64][33];
  const int tiles_c = (Cp + 31) >> 5;
  const int rb = (tile/tiles_c)*64, cb = (tile%tiles_c)*32;
  const int tid = threadIdx.x;
  const bool vec = ((C & 3) == 0);
  #pragma unroll
  for (int i=0;i<2;i++){
    const int idx = tid + i*256;
    const int row = idx>>3, c4 = (idx&7)*4;
    const int c = cb + c4;
    float v0=0.f,v1=0.f,v2=0.f,v3=0.f;
    if (vec && c+3 < C){
      const f32x4 v = *(const f32x4*)&in[(size_t)(rb+row)*C + c];
      v0=v[0]; v1=v[1]; v2=v[2]; v3=v[3];
    } else {
      const float* rp = in + (size_t)(rb+row)*C;
      if (c   < C) v0 = rp[c];
      if (c+1 < C) v1 = rp[c+1];
      if (c+2 < C) v2 = rp[c+2];
      if (c+3 < C) v3 = rp[c+3];
    }
    tb[row][c4]=v0; tb[row][c4+1]=v1; tb[row][c4+2]=v2; tb[row][c4+3]=v3;
  }
  __syncthreads();
  #pragma unroll
  for (int i=0;i<4;i++){
    const int idx = tid + i*256;
    const int cr = idx>>5, p = idx&31;
    const int cc = cb + cr;
    if (cc < Cp){
      union { struct { unsigned short a,b; } s; unsigned int u; } pk;
      pk.s.a = f2bfu(tb[2*p][cr]);
      pk.s.b = f2bfu(tb[2*p+1][cr]);
      *(unsigned int*)&out[(size_t)cc*R + rb + 2*p] = pk.u;
    }
  }
}

// prep block ranges
#define T_WH 864
#define T_WT 864
#define T_WK 288
#define T_WB 3072
#define T_SEQ 1536
#define O_WT  (T_WH)
#define O_WK  (O_WT+T_WT)
#define O_WB  (O_WK+T_WK)
#define O_SEQ (O_WB+T_WB)
#define O_EMB (O_SEQ+T_SEQ)
#define O_ATT (O_EMB+N_*E_)
#define O_VQ  (O_ATT+N_*E_*H_)
#define O_WKAW (O_VQ+D_)
#define O_MISC (O_WKAW+D_)
#define G_PREP (O_MISC+1)

__global__ __launch_bounds__(256) void k_prep(
    const float* __restrict__ seq, const float* __restrict__ attn,
    const int* __restrict__ pos,
    const float* __restrict__ Wq, const float* __restrict__ bq,
    const float* __restrict__ Wk, const float* __restrict__ bk,
    const float* __restrict__ aw, const float* __restrict__ ab,
    const float* __restrict__ Wh, const float* __restrict__ Wt,
    const float* __restrict__ Wb,
    __hip_bfloat16* __restrict__ WhT, __hip_bfloat16* __restrict__ WtT,
    __hip_bfloat16* __restrict__ WkT, __hip_bfloat16* __restrict__ WbT,
    __hip_bfloat16* __restrict__ seqT,
    __hip_bfloat16* __restrict__ ent_bf, __hip_bfloat16* __restrict__ Ambf,
    __hip_bfloat16* __restrict__ att_bf,
    float* __restrict__ vq, float* __restrict__ wk_aw, float* __restrict__ qc2){
  const int b = blockIdx.x;
  const int tid = threadIdx.x;
  if (b < O_WT){ tcvt64(Wh, WhT, K3D_, D_, D_, b); return; }
  if (b < O_WK){ tcvt64(Wt, WtT, K3D_, D_, D_, b-O_WT); return; }
  if (b < O_WB){ tcvt64(Wk, WkT, D_, D_, D_, b-O_WK); return; }
  if (b < O_SEQ){ tcvt64(Wb, WbT, KBL_, NL_, NLP_, b-O_WB); return; }
  if (b < O_EMB){ tcvt64(seq, seqT, N_*C_, D_, D_, b-O_SEQ); return; }
  if (b < O_ATT){
    const int be = b - O_EMB;
    const int n = be >> 5;
    const int* pp = pos + be*M_;
    if (tid < 192){
      const int c4 = tid*4;
      const f32x4 v0 = *(const f32x4*)&seq[((size_t)n*C_ + pp[0])*D_ + c4];
      const f32x4 v1 = *(const f32x4*)&seq[((size_t)n*C_ + pp[1])*D_ + c4];
      const f32x4 v2 = *(const f32x4*)&seq[((size_t)n*C_ + pp[2])*D_ + c4];
      const f32x4 v3 = *(const f32x4*)&seq[((size_t)n*C_ + pp[3])*D_ + c4];
      ushort4v a0,a1,a2,a3,e;
      #pragma unroll
      for (int j=0;j<4;j++){
        a0[j]=f2bfu(v0[j]); a1[j]=f2bfu(v1[j]); a2[j]=f2bfu(v2[j]); a3[j]=f2bfu(v3[j]);
        const float m = fmaxf(fmaxf(v0[j],v1[j]), fmaxf(v2[j],v3[j]));
        const float s = expf(v0[j]-m)+expf(v1[j]-m)+expf(v2[j]-m)+expf(v3[j]-m);
        e[j] = f2bfu(m + logf(s));
      }
      *(ushort4v*)&Ambf[(size_t)(be*4+0)*D_ + c4] = a0;
      *(ushort4v*)&Ambf[(size_t)(be*4+1)*D_ + c4] = a1;
      *(ushort4v*)&Ambf[(size_t)(be*4+2)*D_ + c4] = a2;
      *(ushort4v*)&Ambf[(size_t)(be*4+3)*D_ + c4] = a3;
      *(ushort4v*)&ent_bf[(size_t)be*D_ + c4] = e;
    }
    return;
  }
  if (b < O_VQ){
    const int bb2 = b - O_ATT;
    const int h = bb2 % H_;
    const int ne = bb2 / H_;
    const int n = ne >> 5;
    const int* pp = pos + ne*M_;
    const float* basep = attn + ((size_t)(n*H_+h))*C_*C_;
    const int c4 = tid*4;
    const f32x4 r0 = *(const f32x4*)&basep[(size_t)pp[0]*C_ + c4];
    const f32x4 r1 = *(const f32x4*)&basep[(size_t)pp[1]*C_ + c4];
    const f32x4 r2 = *(const f32x4*)&basep[(size_t)pp[2]*C_ + c4];
    const f32x4 r3 = *(const f32x4*)&basep[(size_t)pp[3]*C_ + c4];
    ushort4v o;
    #pragma unroll
    for (int j=0;j<4;j++) o[j] = f2bfu(0.25f*(r0[j]+r1[j]+r2[j]+r3[j]));
    *(ushort4v*)&att_bf[(size_t)bb2*C_ + c4] = o;
    return;
  }
  if (b < O_WKAW){
    const int k = b - O_VQ;
    float s = 0.f;
    for (int d=tid; d<D_; d+=256) s += Wq[(size_t)k*D_+d]*aw[d];
    s = blockReduceSum256(s);
    if (tid==0) vq[k] = s;
    return;
  }
  if (b < O_MISC){
    const int k = b - O_WKAW;
    float s = 0.f;
    for (int d=tid; d<D_; d+=256) s += Wk[(size_t)k*D_+d]*aw[D_+d];
    s = blockReduceSum256(s);
    if (tid==0) wk_aw[k] = s;
    return;
  }
  {
    float s0 = 0.f, s1 = 0.f;
    for (int d=tid; d<D_; d+=256){ s0 += bq[d]*aw[d]; s1 += bk[d]*aw[D_+d]; }
    s0 = blockReduceSum256(s0);
    s1 = blockReduceSum256(s1);
    if (tid==0){ qc2[0] = s0 + ab[0]; qc2[1] = s1; }
  }
}

// ht_att (bf16 in/out) + kdot[512]
__global__ __launch_bounds__(256) void k_ht2(
    const __hip_bfloat16* __restrict__ att_bf, const int* __restrict__ hts,
    const __hip_bfloat16* __restrict__ Ambf, const float* __restrict__ wk_aw,
    const float* __restrict__ qc2,
    __hip_bfloat16* __restrict__ ht_bf, float* __restrict__ kdot){
  const int b = blockIdx.x, tid = threadIdx.x;
  if (b < NP_){
    const int r = b, n = r >> 8;
    const int he = hts[r*2], te = hts[r*2+1];
    const unsigned short* ha = (const unsigned short*)att_bf + ((size_t)(n*E_+he))*H_*C_;
    const unsigned short* ta = (const unsigned short*)att_bf + ((size_t)(n*E_+te))*H_*C_;
    const int c0 = tid*4;
    float v[4] = {0.f,0.f,0.f,0.f};
    #pragma unroll
    for (int h=0;h<H_;h++){
      const ushort4v a = *(const ushort4v*)&ha[h*C_ + c0];
      const ushort4v t = *(const ushort4v*)&ta[h*C_ + c0];
      #pragma unroll
      for (int j=0;j<4;j++) v[j] = fmaf(bf2f(a[j]), bf2f(t[j]), v[j]);
    }
    float local = 0.f;
    #pragma unroll
    for (int j=0;j<4;j++){ v[j] *= (1.0f/H_); local += v[j]; }
    const float tot = blockReduceSum256(local);
    const float inv = 1.f/(tot + 1e-5f);
    ushort4v o;
    #pragma unroll
    for (int j=0;j<4;j++) o[j] = f2bfu(v[j]*inv);
    *(ushort4v*)&ht_bf[(size_t)r*C_ + c0] = o;
  } else {
    const int g = b - NP_;
    const unsigned short* Am = (const unsigned short*)Ambf + (size_t)g*D_;
    float s = 0.f;
    for (int d=tid; d<D_; d+=256) s += bf2f(Am[d])*wk_aw[d];
    s = blockReduceSum256(s);
    if (tid==0) kdot[g] = s + qc2[1];
  }
}

// fused GEMM1: global_load_lds + XOR-swizzled LDS (linear dest, inv-swz source, swz read)
// work: [0,96): KK = Am@WkT + bk ; [96,288): rs_bf = ht@seqT
__global__ __launch_bounds__(256) void k_gemm1(
    const __hip_bfloat16* __restrict__ Ambf, const __hip_bfloat16* __restrict__ WkT,
    const float* __restrict__ bk, float* __restrict__ KK,
    const __hip_bfloat16* __restrict__ ht_bf, const __hip_bfloat16* __restrict__ seqT,
    __hip_bfloat16* __restrict__ rs_bf){
  __shared__ short As[64*128];
  __shared__ short Bs[64*128];
  const int tid = threadIdx.x;
  const int lam = tid & 63, wv = tid >> 6;
  const int wm = wv >> 1, wn = wv & 1;
  const int lr4 = lam >> 4, c16 = lam & 15;
  const int p = blockIdx.x;
  const int work = (p & 7)*36 + (p >> 3);
  const short *Ap, *Bp;
  int lda, ldb, K, bm, bn;
  bool isKK;
  if (work < 96){
    isKK = true;
    bm = (work/12)*64; bn = (work%12)*64;
    Ap = (const short*)Ambf + (size_t)bm*D_; lda = D_; K = D_;
    Bp = (const short*)WkT + (size_t)bn*D_;  ldb = D_;
  } else {
    isKK = false;
    const int z = work - 96;
    const int n = z/48, rem = z%48, bnI = rem/16, bmI = rem%16;
    bm = n*P_ + (bmI&3)*64; bn = (bnI*4 + (bmI>>2))*64;
    Ap = (const short*)ht_bf + (size_t)bm*C_;            lda = C_;     K = C_;
    Bp = (const short*)seqT + (size_t)bn*(N_*C_) + n*C_; ldb = N_*C_;
  }
  f32x4 acc[2][2] = {};
  for (int k0=0;k0<K;k0+=128){
    __syncthreads();
    if (wv < 2){
      #pragma unroll
      for (int j=0;j<8;j++){
        const int ai = wv*8 + j;
        const int row = ai*4 + lr4;
        const int csw = c16 ^ (row & 15);
        GLOAD_LDS16(Ap + (size_t)row*lda + k0 + csw*8, &As[ai*512]);
      }
    } else {
      #pragma unroll
      for (int j=0;j<8;j++){
        const int bi = (wv-2)*8 + j;
        const int row = bi*4 + lr4;
        const int csw = c16 ^ (row & 15);
        GLOAD_LDS16(Bp + (size_t)row*ldb + k0 + csw*8, &Bs[bi*512]);
      }
    }
    asm volatile("s_waitcnt vmcnt(0)" ::: "memory");
    __syncthreads();
    #pragma unroll
    for (int h=0;h<4;h++){
      short8 af[2], bfv[2];
      #pragma unroll
      for (int f=0;f<2;f++){
        const int rl = lam & 15;
        const int cs = ((4*h + (lam>>4)) ^ rl)*8;
        af[f]  = *(short8*)&As[(wm*32+f*16+rl)*128 + cs];
        bfv[f] = *(short8*)&Bs[(wn*32+f*16+rl)*128 + cs];
      }
      #pragma unroll
      for (int i=0;i<2;i++)
        #pragma unroll
        for (int jj=0;jj<2;jj++)
          acc[i][jj] = __builtin_amdgcn_mfma_f32_16x16x32_bf16(af[i], bfv[jj], acc[i][jj], 0,0,0);
    }
  }
  #pragma unroll
  for (int i=0;i<2;i++)
    #pragma unroll
    for (int jj=0;jj<2;jj++)
      #pragma unroll
      for (int r_=0;r_<4;r_++){
        const int row = bm + wm*32 + i*16 + (lam>>4)*4 + r_;
        const int col = bn + wn*32 + jj*16 + (lam&15);
        const float v = acc[i][jj][r_];
        if (isKK) KK[(size_t)row*D_ + col] = v + bk[col];
        else      rs_bf[(size_t)row*D_ + col] = __float2bfloat16(v);
      }
}

// qdot + softmax (precomputed kdot) + blend
__global__ __launch_bounds__(256) void k_mention(
    const __hip_bfloat16* __restrict__ rs_bf, const float* __restrict__ KK,
    const float* __restrict__ vq, const float* __restrict__ qc2,
    const float* __restrict__ kdot, const int* __restrict__ pos,
    const int* __restrict__ hts,
    __hip_bfloat16* __restrict__ hess, __hip_bfloat16* __restrict__ tess){
  const int r = blockIdx.x, n = r>>8, tid = threadIdx.x;
  const unsigned short* rsp = (const unsigned short*)rs_bf + (size_t)r*D_;
  float s = 0.f;
  for (int d=tid; d<D_; d+=256) s += bf2f(rsp[d])*vq[d];
  const float q = blockReduceSum256(s) + qc2[0];
  #pragma unroll
  for (int side=0;side<2;side++){
    const int e = hts[r*2+side];
    const int base = (n*E_+e)*M_;
    float sc[4];
    #pragma unroll
    for (int m=0;m<4;m++){
      float t = q + kdot[base+m];
      t = (t > 0.f) ? t : 0.01f*t;
      sc[m] = (pos[base+m] != 0) ? t : -1e9f;
    }
    const float mx = fmaxf(fmaxf(sc[0],sc[1]), fmaxf(sc[2],sc[3]));
    float ex[4]; float sum = 0.f;
    #pragma unroll
    for (int m=0;m<4;m++){ ex[m] = expf(sc[m]-mx); sum += ex[m]; }
    const float inv = 1.f/sum;
    const float p0=ex[0]*inv, p1=ex[1]*inv, p2=ex[2]*inv, p3=ex[3]*inv;
    const float* K0 = KK + (size_t)(base+0)*D_;
    const float* K1 = KK + (size_t)(base+1)*D_;
    const float* K2 = KK + (size_t)(base+2)*D_;
    const float* K3 = KK + (size_t)(base+3)*D_;
    __hip_bfloat16* outp = (side ? tess : hess) + (size_t)r*D_;
    for (int d=tid; d<D_; d+=256)
      outp[d] = __float2bfloat16(p0*K0[d] + p1*K1[d] + p2*K2[d] + p3*K3[d]);
  }
}

// z GEMM: global_load_lds + XOR swizzle, gather-fused A, fused bias+tanh, bf16 out
__global__ __launch_bounds__(256) void k_gemm_z(
    const __hip_bfloat16* __restrict__ rs_bf, const __hip_bfloat16* __restrict__ ent_bf,
    const __hip_bfloat16* __restrict__ hess_bf, const __hip_bfloat16* __restrict__ tess_bf,
    const int* __restrict__ hts,
    const __hip_bfloat16* __restrict__ WhT, const __hip_bfloat16* __restrict__ WtT,
    const float* __restrict__ bh, const float* __restrict__ bt,
    __hip_bfloat16* __restrict__ zh, __hip_bfloat16* __restrict__ zt){
  const int p = blockIdx.x;
  const int work = (p & 7)*48 + (p >> 3);
  const int side = work / 192;
  const int w2 = work - side*192;
  const int bn = (w2 / 16)*64;
  const int bm = (w2 & 15)*64;
  const short* BT = (const short*)(side ? WtT : WhT);
  const float* bias = side ? bt : bh;
  unsigned short* Cm = (unsigned short*)(side ? zt : zh);
  const short* hx  = (const short*)(side ? tess_bf : hess_bf);
  const short* rsp = (const short*)rs_bf;
  const short* enp = (const short*)ent_bf;
  __shared__ short As[64*128];
  __shared__ short Bs[64*128];
  __shared__ int e_s[64];
  const int tid = threadIdx.x;
  if (tid < 64) e_s[tid] = hts[(bm+tid)*2 + side];
  __syncthreads();
  const int lam = tid & 63, wv = tid >> 6;
  const int wm = wv >> 1, wn = wv & 1;
  const int lr4 = lam >> 4, c16 = lam & 15;
  const int n4 = bm >> 8;
  f32x4 acc[2][2] = {};
  for (int k0=0;k0<K3D_;k0+=128){
    __syncthreads();
    if (wv < 2){
      #pragma unroll
      for (int j=0;j<8;j++){
        const int ai = wv*8 + j;
        const int row = ai*4 + lr4;
        const int csw = c16 ^ (row & 15);
        const int gk = k0 + csw*8;
        const short* src;
        if (k0 < D_)        src = rsp + (size_t)(bm+row)*D_ + gk;
        else if (k0 < 2*D_) src = enp + ((size_t)(n4*E_ + e_s[row]))*D_ + (gk - D_);
        else                src = hx  + (size_t)(bm+row)*D_ + (gk - 2*D_);
        GLOAD_LDS16(src, &As[ai*512]);
      }
    } else {
      #pragma unroll
      for (int j=0;j<8;j++){
        const int bi = (wv-2)*8 + j;
        const int row = bi*4 + lr4;
        const int csw = c16 ^ (row & 15);
        GLOAD_LDS16(BT + (size_t)(bn+row)*K3D_ + k0 + csw*8, &Bs[bi*512]);
      }
    }
    asm volatile("s_waitcnt vmcnt(0)" ::: "memory");
    __syncthreads();
    #pragma unroll
    for (int h=0;h<4;h++){
      short8 af[2], bfv[2];
      #pragma unroll
      for (int f=0;f<2;f++){
        const int rl = lam & 15;
        const int cs = ((4*h + (lam>>4)) ^ rl)*8;
        af[f]  = *(short8*)&As[(wm*32+f*16+rl)*128 + cs];
        bfv[f] = *(short8*)&Bs[(wn*32+f*16+rl)*128 + cs];
      }
      #pragma unroll
      for (int i=0;i<2;i++)
        #pragma unroll
        for (int jj=0;jj<2;jj++)
          acc[i][jj] = __builtin_amdgcn_mfma_f32_16x16x32_bf16(af[i], bfv[jj], acc[i][jj], 0,0,0);
    }
  }
  #pragma unroll
  for (int i=0;i<2;i++)
    #pragma unroll
    for (int jj=0;jj<2;jj++)
      #pragma unroll
      for (int r_=0;r_<4;r_++){
        const int row = bm + wm*32 + i*16 + (lam>>4)*4 + r_;
        const int col = bn + wn*32 + jj*16 + (lam&15);
        float v = acc[i][jj][r_] + bias[col];
        v = tanhf(v);
        if (side==0) v = tanhf(v);
        Cm[(size_t)row*D_ + col] = f2bfu(v);
      }
}

// bilinear MFMA: bf16 z inputs, bf16 partial out
__global__ __launch_bounds__(256) void k_bilinear(
    const __hip_bfloat16* __restrict__ zh, const __hip_bfloat16* __restrict__ zt,
    const __hip_bfloat16* __restrict__ WbT, __hip_bfloat16* __restrict__ partial){
  const int p = blockIdx.x;
  const int work = (p & 7)*48 + (p >> 3);
  const int kc = work >> 4;
  const int r0 = (work & 15)*64;
  const int blkI = kc >> 1, half = kc & 1;
  __shared__ float zh_s[64][36];
  __shared__ float zt_s[64][68];
  __shared__ short Bs[4][NLP_][40];
  const int tid = threadIdx.x;
  const unsigned short* zhu = (const unsigned short*)zh;
  const unsigned short* ztu = (const unsigned short*)zt;
  for (int idx=tid; idx<64*8; idx+=256){
    const int row = idx>>3, c4 = (idx&7)*4;
    const ushort4v v = *(const ushort4v*)&zhu[(size_t)(r0+row)*D_ + blkI*64 + half*32 + c4];
    #pragma unroll
    for (int j=0;j<4;j++) zh_s[row][c4+j] = bf2f(v[j]);
  }
  for (int idx=tid; idx<64*16; idx+=256){
    const int row = idx>>4, c4 = (idx&15)*4;
    const ushort4v v = *(const ushort4v*)&ztu[(size_t)(r0+row)*D_ + blkI*64 + c4];
    #pragma unroll
    for (int j=0;j<4;j++) zt_s[row][c4+j] = bf2f(v[j]);
  }
  const int w = tid>>6, l = tid&63;
  const int arow = w*16 + (l&15);
  const short* WT = (const short*)WbT;
  const size_t kbase = (size_t)blkI*4096 + half*2048;
  int sl[7], cl[7], k8l[7];
  #pragma unroll
  for (int t=0;t<7;t++){
    const int ci = tid + t*256;
    sl[t] = ci/448;
    const int rem = ci - sl[t]*448;
    cl[t] = rem>>2; k8l[t] = (rem&3)*8;
  }
  short8 pre[7];
  #pragma unroll
  for (int t=0;t<7;t++)
    pre[t] = *(const short8*)&WT[(size_t)cl[t]*KBL_ + kbase + (size_t)sl[t]*32 + k8l[t]];
  f32x4 acc[7] = {};
  for (int g=0; g<16; ++g){
    __syncthreads();
    #pragma unroll
    for (int t=0;t<7;t++) *(short8*)&Bs[sl[t]][cl[t]][k8l[t]] = pre[t];
    __syncthreads();
    if (g < 15){
      #pragma unroll
      for (int t=0;t<7;t++)
        pre[t] = *(const short8*)&WT[(size_t)cl[t]*KBL_ + kbase + (size_t)((g+1)*4+sl[t])*32 + k8l[t]];
    }
    #pragma unroll
    for (int ss=0;ss<4;ss++){
      const int s = g*4 + ss;
      const int iLoc = s>>1;
      const int jj = (s&1)*32 + (l>>4)*8;
      const float a = zh_s[arow][iLoc];
      f32x4 z0 = *(f32x4*)&zt_s[arow][jj];
      f32x4 z1 = *(f32x4*)&zt_s[arow][jj+4];
      short8 afr;
      #pragma unroll
      for (int t=0;t<4;t++) afr[t]   = f2bf(a*z0[t]);
      #pragma unroll
      for (int t=0;t<4;t++) afr[4+t] = f2bf(a*z1[t]);
      #pragma unroll
      for (int nf=0;nf<7;nf++){
        const short8 bfr = *(short8*)&Bs[ss][nf*16 + (l&15)][(l>>4)*8];
        acc[nf] = __builtin_amdgcn_mfma_f32_16x16x32_bf16(afr, bfr, acc[nf], 0,0,0);
      }
    }
  }
  unsigned short* pp = (unsigned short*)partial;
  #pragma unroll
  for (int nf=0;nf<7;nf++)
    #pragma unroll
    for (int r_=0;r_<4;r_++){
      const int row = r0 + w*16 + (l>>4)*4 + r_;
      const int col = nf*16 + (l&15);
      pp[((size_t)kc*NP_ + row)*NLP_ + col] = f2bfu(acc[nf][r_]);
    }
}

__global__ __launch_bounds__(256) void k_reduce(const __hip_bfloat16* __restrict__ partial,
    const float* __restrict__ bb, float* __restrict__ out){
  const int idx = blockIdx.x*256 + threadIdx.x;
  if (idx >= NP_*NL_) return;
  const int r = idx / NL_;
  const int l = idx - r*NL_;
  const unsigned short* pp = (const unsigned short*)partial;
  float s = bb[l];
  #pragma unroll
  for (int kc=0;kc<24;kc++) s += bf2f(pp[((size_t)kc*NP_ + r)*NLP_ + l]);
  out[idx] = s;
}

extern "C" void kernel_launch(void* const* d_in, const int* in_sizes, int n_in,
                              void* d_out, int out_size, void* d_ws, size_t ws_size,
                              hipStream_t stream){
  const float* seq  = (const float*)d_in[0];
  const float* attn = (const float*)d_in[1];
  const int*   pos  = (const int*)d_in[2];
  const int*   hts  = (const int*)d_in[3];
  const float* Wq = (const float*)d_in[4];
  const float* bq = (const float*)d_in[5];
  const float* Wk = (const float*)d_in[6];
  const float* bk = (const float*)d_in[7];
  const float* aw = (const float*)d_in[8];
  const float* ab = (const float*)d_in[9];
  const float* Wh = (const float*)d_in[10];
  const float* bh = (const float*)d_in[11];
  const float* Wt = (const float*)d_in[12];
  const float* bt = (const float*)d_in[13];
  const float* Wb = (const float*)d_in[14];
  const float* bb = (const float*)d_in[15];
  float* out = (float*)d_out;

  char* base = (char*)d_ws;
  size_t off = 0;
  auto alloc = [&](size_t bytes)->void*{
    void* p = base + off;
    off += (bytes + 255) & ~(size_t)255;
    return p;
  };
  __hip_bfloat16* WhT   = (__hip_bfloat16*)alloc((size_t)D_*K3D_*2);
  __hip_bfloat16* WtT   = (__hip_bfloat16*)alloc((size_t)D_*K3D_*2);
  __hip_bfloat16* WkT   = (__hip_bfloat16*)alloc((size_t)D_*D_*2);
  __hip_bfloat16* WbT   = (__hip_bfloat16*)alloc((size_t)NLP_*KBL_*2);
  __hip_bfloat16* seqT  = (__hip_bfloat16*)alloc((size_t)D_*N_*C_*2);
  __hip_bfloat16* ent_bf= (__hip_bfloat16*)alloc((size_t)N_*E_*D_*2);
  __hip_bfloat16* att_bf= (__hip_bfloat16*)alloc((size_t)N_*E_*H_*C_*2);
  __hip_bfloat16* ht_bf = (__hip_bfloat16*)alloc((size_t)NP_*C_*2);
  __hip_bfloat16* Ambf  = (__hip_bfloat16*)alloc((size_t)N_*E_*M_*D_*2);
  float* KK             = (float*)alloc((size_t)N_*E_*M_*D_*4);
  float* vq             = (float*)alloc(D_*4);
  float* wk_aw          = (float*)alloc(D_*4);
  float* qc2            = (float*)alloc(256);
  float* kdot           = (float*)alloc(512*4);
  __hip_bfloat16* rs_bf = (__hip_bfloat16*)alloc((size_t)NP_*D_*2);
  __hip_bfloat16* hess  = (__hip_bfloat16*)alloc((size_t)NP_*D_*2);
  __hip_bfloat16* tess  = (__hip_bfloat16*)alloc((size_t)NP_*D_*2);
  __hip_bfloat16* zh    = (__hip_bfloat16*)alloc((size_t)NP_*D_*2);
  __hip_bfloat16* zt    = (__hip_bfloat16*)alloc((size_t)NP_*D_*2);
  __hip_bfloat16* partial = (__hip_bfloat16*)alloc((size_t)24*NP_*NLP_*2);
  (void)ws_size; (void)in_sizes; (void)n_in; (void)out_size;

  k_prep<<<G_PREP, 256, 0, stream>>>(seq, attn, pos, Wq, bq, Wk, bk, aw, ab, Wh, Wt, Wb,
                                     WhT, WtT, WkT, WbT, seqT, ent_bf, Ambf, att_bf,
                                     vq, wk_aw, qc2);
  k_ht2<<<NP_ + 512, 256, 0, stream>>>(att_bf, hts, Ambf, wk_aw, qc2, ht_bf, kdot);
  k_gemm1<<<288, 256, 0, stream>>>(Ambf, WkT, bk, KK, ht_bf, seqT, rs_bf);
  k_mention<<<NP_, 256, 0, stream>>>(rs_bf, KK, vq, qc2, kdot, pos, hts, hess, tess);
  k_gemm_z<<<384, 256, 0, stream>>>(rs_bf, ent_bf, hess, tess, hts,
                                    WhT, WtT, bh, bt, zh, zt);
  k_bilinear<<<384, 256, 0, stream>>>(zh, zt, WbT, partial);
  k_reduce<<<(NP_*NL_+255)/256, 256, 0, stream>>>(partial, bb, out);
}